// Round 12
// baseline (99.985 us; speedup 1.0000x reference)
//
#include <hip/hip_runtime.h>
#include <math.h>

#define S_DIM 2048
#define L_DIM 4096
#define D_DIM 500
#define NPOI 10000
#define NTIME 48
#define EXP_SHIFT 40.0f

typedef __attribute__((ext_vector_type(8))) short short8;
typedef __attribute__((ext_vector_type(16))) float f32x16;

#define A_BYTES 4194304       // 8 mb x 16 ks x 32768
#define PLANE_BYTES 12582912  // A (4 MB) + B (32 nb x 16 ks x 16384)

// ---------------- helpers ----------------
__device__ __forceinline__ float wave_max(float v) {
#pragma unroll
  for (int o = 32; o > 0; o >>= 1) v = fmaxf(v, __shfl_down(v, o, 64));
  return v;
}
__device__ __forceinline__ float wave_sum(float v) {
#pragma unroll
  for (int o = 32; o > 0; o >>= 1) v += __shfl_down(v, o, 64);
  return v;
}
__device__ __forceinline__ float half_sum(float v) {  // sum within 32-lane half
#pragma unroll
  for (int o = 16; o > 0; o >>= 1) v += __shfl_xor(v, o, 64);
  return v;
}
__device__ __forceinline__ short f2bf(float x) {  // RNE f32 -> bf16 bits
  union { float f; unsigned u; } v;
  v.f = x;
  const unsigned r = v.u + 0x7fffu + ((v.u >> 16) & 1u);
  return (short)(r >> 16);
}
__device__ __forceinline__ float bf2f(short h) {
  union { unsigned u; float f; } v;
  v.u = ((unsigned)(unsigned short)h) << 16;
  return v.f;
}

// ------- split (f32 -> GEMM-tiled swizzled hi/lo bf16 planes) + table -----
__global__ __launch_bounds__(256) void split_table_kernel(
    const float* __restrict__ U, const float* __restrict__ Id,
    const float* __restrict__ w1p, const float* __restrict__ soc,
    const float* __restrict__ w2p, const int* __restrict__ his_t,
    const float* __restrict__ T, short* __restrict__ planes,
    float* __restrict__ bias, float* __restrict__ P) {
  const int tid = threadIdx.x;
  if (blockIdx.x == gridDim.x - 1) {  // ---- time table block ----
    __shared__ int cnt[NTIME];
    __shared__ float Ts[NTIME * NTIME];
    if (tid < NTIME) cnt[tid] = 0;
    __syncthreads();
    for (int l = tid; l < L_DIM; l += 256) atomicAdd(&cnt[his_t[l]], 1);
    for (int i = tid; i < NTIME * NTIME; i += 256) Ts[i] = T[i];
    __syncthreads();
    if (tid < NTIME) {
      float m = -1e30f;
      for (int t = 0; t < NTIME; ++t) m = fmaxf(m, Ts[tid * NTIME + t]);
      float den = 0.f;
      for (int t = 0; t < NTIME; ++t)
        den += (float)cnt[t] * __expf(Ts[tid * NTIME + t] - m);
      const float inv = 1.0f / den;
      for (int t = 0; t < NTIME; ++t)
        P[tid * NTIME + t] = __expf(Ts[tid * NTIME + t] - m) * inv;
    }
    return;
  }
  const int chunk = blockIdx.x * 256 + tid;
  const int row = chunk >> 6;  // 0..6143
  const int lq = chunk & 63;   // 8-elem granule index along K
  const bool isA = row < S_DIM;
  const float scale = isA ? w1p[0] : 1.0f;
  const float* src = isA ? (U + (size_t)row * D_DIM)
                         : (Id + (size_t)(row - S_DIM) * D_DIM);
  const int k0 = lq * 8;
  float dot = 0.f;
  short h[8], l[8];
#pragma unroll
  for (int e = 0; e < 8; ++e) {
    const int k = k0 + e;
    const float v = (k < D_DIM) ? src[k] : 0.0f;
    if (!isA && k < D_DIM) dot += v * soc[k];
    const float x = scale * v;
    const short hb = f2bf(x);
    h[e] = hb;
    l[e] = f2bf(x - bf2f(hb));
  }
  const int ks = lq >> 2, g = lq & 3;
  if (isA) {
    const int mb = row >> 8, rin = row & 255;
    const int gs = g ^ (rin & 3) ^ ((rin >> 2) & 3);
    char* base =
        (char*)planes + (size_t)(mb * 16 + ks) * 32768 + rin * 64 + gs * 16;
    *reinterpret_cast<int4*>(base) = *reinterpret_cast<const int4*>(h);
    *reinterpret_cast<int4*>(base + 16384) = *reinterpret_cast<const int4*>(l);
  } else {
    const int rb = row - S_DIM;
    const int nb = rb >> 7, rin = rb & 127;
    const int gs = g ^ (rin & 3) ^ ((rin >> 2) & 3);
    char* base = (char*)planes + A_BYTES + (size_t)(nb * 16 + ks) * 16384 +
                 rin * 64 + gs * 16;
    *reinterpret_cast<int4*>(base) = *reinterpret_cast<const int4*>(h);
    *reinterpret_cast<int4*>(base + 8192) = *reinterpret_cast<const int4*>(l);
    const float d = wave_sum(dot);
    if ((tid & 63) == 0) bias[rb] = w2p[0] * d;
  }
}

// ======= FUSED: GEMM (every 5th block) || loc/time (other blocks) =========
// GEMM role: 128x128 tile, 8 waves (2m x 4n, 64x32 each), BK=32, dbuf 64KB
// -> 2 blocks/CU co-residency with loc blocks (the overlap lever).
// Epilogue: exp(E+bias-40) f32 to user plane + per-(row, nb, n-wave) partials.
// loc role: stage 40KB poi row to LDS, gather+softmax -> out_loc; time plane
// via Prow gather -> out_time.
__global__ __launch_bounds__(512, 2) void fused_gemm_loc(
    const short* __restrict__ planes, const float* __restrict__ bias,
    float* __restrict__ part, float* __restrict__ outX,
    const int* __restrict__ cur, const int* __restrict__ his,
    const float* __restrict__ poi, const int* __restrict__ cur_t,
    const int* __restrict__ his_t, const float* __restrict__ P,
    float* __restrict__ out_loc, float* __restrict__ out_time) {
  __shared__ __attribute__((aligned(1024))) char lds[65536];
  __shared__ float redm[8];
  __shared__ float reds[8];
  __shared__ float Prow[NTIME];
  const int tid = threadIdx.x;
  const int lane = tid & 63;
  const int wid = tid >> 6;
  const int gb = blockIdx.x;

  if (gb % 5 == 0) {
    // ---------------- GEMM role ----------------
    const int gi = gb / 5;  // 0..511
    const int nb = gi & 31, mbb = gi >> 5;
    const int mb256 = mbb >> 1, hh = mbb & 1;
    const int bm = mbb * 128, bn = nb * 128;
    const char* gA =
        (const char*)planes + (size_t)mb256 * 16 * 32768 + hh * 8192;
    const char* gB = (const char*)planes + A_BYTES + (size_t)nb * 16 * 16384;
    const int wm = (wid >> 2) * 64;   // 0 or 64
    const int wn = (wid & 3) * 32;    // 0..96
    const int r32 = lane & 31;
    const int khl = lane >> 5;

    f32x16 acc[2] = {};

#define STAGE(ks_, buf_)                                                      \
  {                                                                           \
    const char* gAk = gA + (size_t)(ks_)*32768;                               \
    const char* gBk = gB + (size_t)(ks_)*16384;                               \
    char* _dst = lds + (buf_)*32768;                                          \
    _Pragma("unroll") for (int q = 0; q < 4; ++q) {                           \
      const int off = (q * 512 + tid) * 16;                                   \
      const char* src = (q == 0)   ? (gAk + off)                              \
                        : (q == 1) ? (gAk + off + 8192)                       \
                                   : (gBk + (off - 16384));                   \
      __builtin_amdgcn_global_load_lds(                                       \
          (const __attribute__((address_space(1))) unsigned*)src,             \
          (__attribute__((address_space(3))) unsigned*)(_dst + off), 16, 0,   \
          0);                                                                 \
    }                                                                         \
  }

    STAGE(0, 0);
    __syncthreads();
    int buf = 0;
    for (int ks = 0; ks < 16; ++ks) {
      if (ks < 15) STAGE(ks + 1, buf ^ 1);
      const char* La = lds + buf * 32768;
      const char* Lb = La + 16384;
#pragma unroll
      for (int s16 = 0; s16 < 2; ++s16) {
        short8 ah[2], al[2], bh, bl;
#pragma unroll
        for (int i = 0; i < 2; ++i) {
          const int ra = wm + i * 32 + r32;
          const int ga = ((s16 * 2 + khl) ^ (ra & 3) ^ ((ra >> 2) & 3)) * 16;
          ah[i] = *reinterpret_cast<const short8*>(La + ra * 64 + ga);
          al[i] = *reinterpret_cast<const short8*>(La + 8192 + ra * 64 + ga);
        }
        const int rbb = wn + r32;
        const int gbx = ((s16 * 2 + khl) ^ (rbb & 3) ^ ((rbb >> 2) & 3)) * 16;
        bh = *reinterpret_cast<const short8*>(Lb + rbb * 64 + gbx);
        bl = *reinterpret_cast<const short8*>(Lb + 8192 + rbb * 64 + gbx);
#pragma unroll
        for (int i = 0; i < 2; ++i) {
          acc[i] =
              __builtin_amdgcn_mfma_f32_32x32x16_bf16(ah[i], bh, acc[i], 0, 0, 0);
          acc[i] =
              __builtin_amdgcn_mfma_f32_32x32x16_bf16(ah[i], bl, acc[i], 0, 0, 0);
          acc[i] =
              __builtin_amdgcn_mfma_f32_32x32x16_bf16(al[i], bh, acc[i], 0, 0, 0);
        }
      }
      __syncthreads();
      buf ^= 1;
    }
#undef STAGE

    // epilogue: x = exp(E + bias - 40) f32; per-(row, nb, n-wave) partials.
    // C/D: col=lane&31, row=(reg&3)+8*(reg>>2)+4*(lane>>5) (r3-r11 validated)
    const float bj = bias[bn + wn + r32];
    const int slot = nb * 4 + (wid & 3);
#pragma unroll
    for (int i = 0; i < 2; ++i) {
#pragma unroll
      for (int reg = 0; reg < 16; ++reg) {
        const int rowm =
            bm + wm + i * 32 + 4 * khl + (reg & 3) + 8 * (reg >> 2);
        const float e = __expf(acc[i][reg] + bj - EXP_SHIFT);
        outX[(size_t)rowm * L_DIM + bn + wn + r32] = e;
        const float hs = half_sum(e);
        if (r32 == 0) part[(size_t)rowm * 128 + slot] = hs;
      }
    }
  } else {
    // ---------------- loc/time role ----------------
    const int s = (gb / 5) * 4 + (gb % 5) - 1;  // 0..2047
    float* rowbuf = (float*)lds;                // 40000 B
    if (tid < NTIME) Prow[tid] = P[cur_t[s] * NTIME + tid];
    const float* row = poi + (size_t)cur[s] * NPOI;  // 40000B-aligned
    for (int i = tid; i < NPOI / 4; i += 512)
      reinterpret_cast<float4*>(rowbuf)[i] =
          reinterpret_cast<const float4*>(row)[i];
    __syncthreads();
    float v[8];
    float lmax = -1e30f;
#pragma unroll
    for (int j = 0; j < 8; ++j) {
      const int l = j * 512 + tid;
      const float d = rowbuf[his[l]];
      const float e = (d != 0.0f) ? (1.0f / d) : 1e-6f;
      v[j] = e;
      lmax = fmaxf(lmax, e);
    }
    lmax = wave_max(lmax);
    if (lane == 0) redm[wid] = lmax;
    __syncthreads();
    float m = redm[0];
#pragma unroll
    for (int w = 1; w < 8; ++w) m = fmaxf(m, redm[w]);
    float lsum = 0.f;
#pragma unroll
    for (int j = 0; j < 8; ++j) {
      v[j] = __expf(v[j] - m);
      lsum += v[j];
    }
    lsum = wave_sum(lsum);
    if (lane == 0) reds[wid] = lsum;
    __syncthreads();
    float tot = reds[0];
#pragma unroll
    for (int w = 1; w < 8; ++w) tot += reds[w];
    const float inv = 1.0f / tot;
    float* ol = out_loc + (size_t)s * L_DIM;
    float* ot = out_time + (size_t)s * L_DIM;
#pragma unroll
    for (int j = 0; j < 8; ++j) {
      const int l = j * 512 + tid;
      ol[l] = v[j] * inv;
      ot[l] = Prow[his_t[l]];
    }
  }
}

// ------- K3: user-plane normalize from partials (f32 in place) ------------
__global__ __launch_bounds__(256) void normalize_kernel(
    const float* __restrict__ part, float* __restrict__ outU) {
  __shared__ float sinv_sh;
  const int s = blockIdx.x;
  const int tid = threadIdx.x;
  if (tid < 64) {
    float p = part[(size_t)s * 128 + tid] + part[(size_t)s * 128 + 64 + tid];
    p = wave_sum(p);
    if (tid == 0) sinv_sh = 1.0f / p;
  }
  __syncthreads();
  const float sinv = sinv_sh;
  float* ou = outU + (size_t)s * L_DIM;
#pragma unroll
  for (int q = 0; q < 4; ++q) {
    float4 x = *reinterpret_cast<const float4*>(&ou[(q * 256 + tid) * 4]);
    x.x *= sinv; x.y *= sinv; x.z *= sinv; x.w *= sinv;
    *reinterpret_cast<float4*>(&ou[(q * 256 + tid) * 4]) = x;
  }
}

// ================== FALLBACK PATH (r9, proven) ============================
__global__ __launch_bounds__(512, 2) void user_gemm_fb(
    const short* __restrict__ planes, const float* __restrict__ bias,
    float* __restrict__ part, float* __restrict__ outX) {
  __shared__ __attribute__((aligned(1024))) char lds[2 * 49152];
  const int tid = threadIdx.x;
  const int lane = tid & 63;
  const int wid = tid >> 6;
  const int ob = (blockIdx.x & 7) * 32 + (blockIdx.x >> 3);
  const int nb = ob >> 3;
  const int mb = ob & 7;
  const int bm = mb * 256, bn = nb * 128;
  const char* gA = (const char*)planes + (size_t)mb * 16 * 32768;
  const char* gB = (const char*)planes + A_BYTES + (size_t)nb * 16 * 16384;
  const int wm = (wid >> 1) * 64;
  const int wn = (wid & 1) * 64;
  const int r32 = lane & 31;
  const int khl = lane >> 5;
  f32x16 acc[2][2] = {};
#define STAGE(ks_, buf_)                                                      \
  {                                                                           \
    const int _ks = (ks_);                                                    \
    char* _dst = lds + (buf_)*49152;                                          \
    _Pragma("unroll") for (int q = 0; q < 6; ++q) {                           \
      const int off = (q * 512 + tid) * 16;                                   \
      if (q < 4) {                                                            \
        __builtin_amdgcn_global_load_lds(                                     \
            (const __attribute__((address_space(1))) unsigned*)(gA +          \
                (size_t)_ks * 32768 + off),                                   \
            (__attribute__((address_space(3))) unsigned*)(_dst + off), 16, 0, \
            0);                                                               \
      } else {                                                                \
        __builtin_amdgcn_global_load_lds(                                     \
            (const __attribute__((address_space(1))) unsigned*)(gB +          \
                (size_t)_ks * 16384 + (off - 32768)),                         \
            (__attribute__((address_space(3))) unsigned*)(_dst + off), 16, 0, \
            0);                                                               \
      }                                                                       \
    }                                                                         \
  }
  STAGE(0, 0);
  __syncthreads();
  int buf = 0;
  for (int ks = 0; ks < 16; ++ks) {
    if (ks < 15) STAGE(ks + 1, buf ^ 1);
    const char* La = lds + buf * 49152;
    const char* Lb = La + 32768;
#pragma unroll
    for (int s16 = 0; s16 < 2; ++s16) {
      short8 ah[2], al[2], bh[2], bl[2];
#pragma unroll
      for (int i = 0; i < 2; ++i) {
        const int ra = wm + i * 32 + r32;
        const int ga = ((s16 * 2 + khl) ^ (ra & 3) ^ ((ra >> 2) & 3)) * 16;
        ah[i] = *reinterpret_cast<const short8*>(La + ra * 64 + ga);
        al[i] = *reinterpret_cast<const short8*>(La + 16384 + ra * 64 + ga);
        const int rbb = wn + i * 32 + r32;
        const int gbx = ((s16 * 2 + khl) ^ (rbb & 3) ^ ((rbb >> 2) & 3)) * 16;
        bh[i] = *reinterpret_cast<const short8*>(Lb + rbb * 64 + gbx);
        bl[i] = *reinterpret_cast<const short8*>(Lb + 8192 + rbb * 64 + gbx);
      }
#pragma unroll
      for (int i = 0; i < 2; ++i)
#pragma unroll
        for (int j = 0; j < 2; ++j) {
          acc[i][j] = __builtin_amdgcn_mfma_f32_32x32x16_bf16(
              ah[i], bh[j], acc[i][j], 0, 0, 0);
          acc[i][j] = __builtin_amdgcn_mfma_f32_32x32x16_bf16(
              ah[i], bl[j], acc[i][j], 0, 0, 0);
          acc[i][j] = __builtin_amdgcn_mfma_f32_32x32x16_bf16(
              al[i], bh[j], acc[i][j], 0, 0, 0);
        }
    }
    __syncthreads();
    buf ^= 1;
  }
#undef STAGE
  const int slot = nb * 2 + (wn >> 6);
  float bj[2];
#pragma unroll
  for (int j = 0; j < 2; ++j) bj[j] = bias[bn + wn + j * 32 + r32];
#pragma unroll
  for (int i = 0; i < 2; ++i) {
#pragma unroll
    for (int reg = 0; reg < 16; ++reg) {
      const int rowm = bm + wm + i * 32 + 4 * khl + (reg & 3) + 8 * (reg >> 2);
      const float e0 = __expf(acc[i][0][reg] + bj[0] - EXP_SHIFT);
      const float e1 = __expf(acc[i][1][reg] + bj[1] - EXP_SHIFT);
      outX[(size_t)rowm * L_DIM + bn + wn + r32] = e0;
      outX[(size_t)rowm * L_DIM + bn + wn + 32 + r32] = e1;
      const float hs = half_sum(e0 + e1);
      if (r32 == 0) part[(size_t)rowm * 64 + slot] = hs;
    }
  }
}

__global__ __launch_bounds__(256) void finalize_fb(
    const int* __restrict__ cur, const int* __restrict__ his,
    const float* __restrict__ poi, const int* __restrict__ cur_t,
    const int* __restrict__ his_t, const float* __restrict__ P,
    const float* __restrict__ part, float* __restrict__ out_loc,
    float* __restrict__ out_time, float* __restrict__ out_user) {
  __shared__ __attribute__((aligned(16))) float rowbuf[NPOI];
  __shared__ float Prow[NTIME];
  __shared__ float redm[4];
  __shared__ float reds[4];
  __shared__ float sinv_sh;
  const int s = blockIdx.x;
  const int tid = threadIdx.x;
  if (tid < NTIME) Prow[tid] = P[cur_t[s] * NTIME + tid];
  if (tid < 64) {
    float p = part[(size_t)s * 64 + tid];
    p = wave_sum(p);
    if (tid == 0) sinv_sh = 1.0f / p;
  }
  const float* row = poi + (size_t)cur[s] * NPOI;
  for (int i = tid; i < NPOI / 4; i += 256)
    *reinterpret_cast<float4*>(&rowbuf[i * 4]) =
        *reinterpret_cast<const float4*>(row + i * 4);
  __syncthreads();
  const float sinv = sinv_sh;
  float* ou = out_user + (size_t)s * L_DIM;
#pragma unroll
  for (int q = 0; q < 4; ++q) {
    float4 x = *reinterpret_cast<const float4*>(&ou[(q * 256 + tid) * 4]);
    x.x *= sinv; x.y *= sinv; x.z *= sinv; x.w *= sinv;
    *reinterpret_cast<float4*>(&ou[(q * 256 + tid) * 4]) = x;
  }
  float v[16];
  float lmax = -1e30f;
#pragma unroll
  for (int j = 0; j < 16; ++j) {
    const int l = j * 256 + tid;
    const float d = rowbuf[his[l]];
    const float e = (d != 0.0f) ? (1.0f / d) : 1e-6f;
    v[j] = e;
    lmax = fmaxf(lmax, e);
  }
  lmax = wave_max(lmax);
  if ((tid & 63) == 0) redm[tid >> 6] = lmax;
  __syncthreads();
  const float m = fmaxf(fmaxf(redm[0], redm[1]), fmaxf(redm[2], redm[3]));
  float lsum = 0.f;
#pragma unroll
  for (int j = 0; j < 16; ++j) {
    v[j] = __expf(v[j] - m);
    lsum += v[j];
  }
  lsum = wave_sum(lsum);
  if ((tid & 63) == 0) reds[tid >> 6] = lsum;
  __syncthreads();
  const float inv = 1.0f / (reds[0] + reds[1] + reds[2] + reds[3]);
  float* ol = out_loc + (size_t)s * L_DIM;
  float* ot = out_time + (size_t)s * L_DIM;
#pragma unroll
  for (int j = 0; j < 16; ++j) {
    const int l = j * 256 + tid;
    ol[l] = v[j] * inv;
    ot[l] = Prow[his_t[l]];
  }
}

extern "C" void kernel_launch(void* const* d_in, const int* in_sizes, int n_in,
                              void* d_out, int out_size, void* d_ws,
                              size_t ws_size, hipStream_t stream) {
  const int* his = (const int*)d_in[0];
  const int* cur = (const int*)d_in[1];
  const int* his_t = (const int*)d_in[2];
  const int* cur_t = (const int*)d_in[3];
  const float* poi = (const float*)d_in[4];
  const float* tsim = (const float*)d_in[5];
  const float* uemb = (const float*)d_in[6];
  const float* idemb = (const float*)d_in[7];
  const float* soc = (const float*)d_in[8];
  const float* w1 = (const float*)d_in[9];
  const float* w2 = (const float*)d_in[10];

  float* out = (float*)d_out;
  float* out_loc = out;
  float* out_time = out + (size_t)S_DIM * L_DIM;
  float* out_user = out + 2 * (size_t)S_DIM * L_DIM;

  // fused path needs: planes 12.58MB | bias | P | part(S*128) ~= 13.66MB
  const size_t fused_aux = (size_t)(L_DIM + NTIME * NTIME + S_DIM * 128) * 4;
  const size_t fb_aux = (size_t)(L_DIM + NTIME * NTIME + S_DIM * 64) * 4;

  if (ws_size >= PLANE_BYTES + fused_aux) {
    short* planes = (short*)d_ws;
    float* bias = (float*)((char*)d_ws + PLANE_BYTES);
    float* P = bias + L_DIM;
    float* part = P + NTIME * NTIME;
    hipLaunchKernelGGL(split_table_kernel,
                       dim3((S_DIM + L_DIM) * 64 / 256 + 1), dim3(256), 0,
                       stream, uemb, idemb, w1, soc, w2, his_t, tsim, planes,
                       bias, P);
    hipLaunchKernelGGL(fused_gemm_loc, dim3(2560), dim3(512), 0, stream,
                       planes, bias, part, out_user, cur, his, poi, cur_t,
                       his_t, P, out_loc, out_time);
    hipLaunchKernelGGL(normalize_kernel, dim3(S_DIM), dim3(256), 0, stream,
                       part, out_user);
  } else {
    // r9 fallback: planes may live in out_loc (written only at the end)
    short* planes;
    float* bias;
    if (ws_size >= PLANE_BYTES + fb_aux) {
      planes = (short*)d_ws;
      bias = (float*)((char*)d_ws + PLANE_BYTES);
    } else {
      planes = (short*)out_loc;
      bias = (float*)d_ws;
    }
    float* P = bias + L_DIM;
    float* part = P + NTIME * NTIME;
    hipLaunchKernelGGL(split_table_kernel,
                       dim3((S_DIM + L_DIM) * 64 / 256 + 1), dim3(256), 0,
                       stream, uemb, idemb, w1, soc, w2, his_t, tsim, planes,
                       bias, P);
    hipLaunchKernelGGL(user_gemm_fb, dim3(256), dim3(512), 0, stream, planes,
                       bias, part, out_user);
    hipLaunchKernelGGL(finalize_fb, dim3(S_DIM), dim3(256), 0, stream, cur,
                       his, poi, cur_t, his_t, P, part, out_loc, out_time,
                       out_user);
  }
}

// Round 13
// 87.557 us; speedup vs baseline: 1.1419x; 1.1419x over previous
//
#include <hip/hip_runtime.h>
#include <math.h>

#define S_DIM 2048
#define L_DIM 4096
#define D_DIM 500
#define NPOI 10000
#define NTIME 48
#define EXP_SHIFT 40.0f

typedef __attribute__((ext_vector_type(8))) short short8;
typedef __attribute__((ext_vector_type(16))) float f32x16;

#define A_BYTES 4194304       // 8 mb x 16 ks x 32768
#define PLANE_BYTES 12582912  // A (4 MB) + B (32 nb x 16 ks x 16384)
#define LDSBUF 49152          // [Ahi 16K | Alo 16K | Bhi 8K | Blo 8K]

// ---------------- helpers ----------------
__device__ __forceinline__ float wave_max(float v) {
#pragma unroll
  for (int o = 32; o > 0; o >>= 1) v = fmaxf(v, __shfl_down(v, o, 64));
  return v;
}
__device__ __forceinline__ float wave_sum(float v) {
#pragma unroll
  for (int o = 32; o > 0; o >>= 1) v += __shfl_down(v, o, 64);
  return v;
}
__device__ __forceinline__ float half_sum(float v) {  // sum within 32-lane half
#pragma unroll
  for (int o = 16; o > 0; o >>= 1) v += __shfl_xor(v, o, 64);
  return v;
}
__device__ __forceinline__ short f2bf(float x) {  // RNE f32 -> bf16 bits
  union { float f; unsigned u; } v;
  v.f = x;
  const unsigned r = v.u + 0x7fffu + ((v.u >> 16) & 1u);
  return (short)(r >> 16);
}
__device__ __forceinline__ float bf2f(short h) {
  union { unsigned u; float f; } v;
  v.u = ((unsigned)(unsigned short)h) << 16;
  return v.f;
}

// ------- split (f32 -> GEMM-tiled swizzled hi/lo bf16 planes) + table -----
__global__ __launch_bounds__(256) void split_table_kernel(
    const float* __restrict__ U, const float* __restrict__ Id,
    const float* __restrict__ w1p, const float* __restrict__ soc,
    const float* __restrict__ w2p, const int* __restrict__ his_t,
    const float* __restrict__ T, short* __restrict__ planes,
    float* __restrict__ bias, float* __restrict__ P) {
  const int tid = threadIdx.x;
  if (blockIdx.x == gridDim.x - 1) {  // ---- time table block ----
    __shared__ int cnt[NTIME];
    __shared__ float Ts[NTIME * NTIME];
    if (tid < NTIME) cnt[tid] = 0;
    __syncthreads();
    for (int l = tid; l < L_DIM; l += 256) atomicAdd(&cnt[his_t[l]], 1);
    for (int i = tid; i < NTIME * NTIME; i += 256) Ts[i] = T[i];
    __syncthreads();
    if (tid < NTIME) {
      float m = -1e30f;
      for (int t = 0; t < NTIME; ++t) m = fmaxf(m, Ts[tid * NTIME + t]);
      float den = 0.f;
      for (int t = 0; t < NTIME; ++t)
        den += (float)cnt[t] * __expf(Ts[tid * NTIME + t] - m);
      const float inv = 1.0f / den;
      for (int t = 0; t < NTIME; ++t)
        P[tid * NTIME + t] = __expf(Ts[tid * NTIME + t] - m) * inv;
    }
    return;
  }
  const int chunk = blockIdx.x * 256 + tid;
  const int row = chunk >> 6;  // 0..6143
  const int lq = chunk & 63;   // 8-elem granule index along K
  const bool isA = row < S_DIM;
  const float scale = isA ? w1p[0] : 1.0f;
  const float* src = isA ? (U + (size_t)row * D_DIM)
                         : (Id + (size_t)(row - S_DIM) * D_DIM);
  const int k0 = lq * 8;
  float dot = 0.f;
  short h[8], l[8];
#pragma unroll
  for (int e = 0; e < 8; ++e) {
    const int k = k0 + e;
    const float v = (k < D_DIM) ? src[k] : 0.0f;
    if (!isA && k < D_DIM) dot += v * soc[k];
    const float x = scale * v;
    const short hb = f2bf(x);
    h[e] = hb;
    l[e] = f2bf(x - bf2f(hb));
  }
  const int ks = lq >> 2, g = lq & 3;
  if (isA) {
    const int mb = row >> 8, rin = row & 255;
    const int gs = g ^ (rin & 3) ^ ((rin >> 2) & 3);
    char* base =
        (char*)planes + (size_t)(mb * 16 + ks) * 32768 + rin * 64 + gs * 16;
    *reinterpret_cast<int4*>(base) = *reinterpret_cast<const int4*>(h);
    *reinterpret_cast<int4*>(base + 16384) = *reinterpret_cast<const int4*>(l);
  } else {
    const int rb = row - S_DIM;
    const int nb = rb >> 7, rin = rb & 127;
    const int gs = g ^ (rin & 3) ^ ((rin >> 2) & 3);
    char* base = (char*)planes + A_BYTES + (size_t)(nb * 16 + ks) * 16384 +
                 rin * 64 + gs * 16;
    *reinterpret_cast<int4*>(base) = *reinterpret_cast<const int4*>(h);
    *reinterpret_cast<int4*>(base + 8192) = *reinterpret_cast<const int4*>(l);
    const float d = wave_sum(dot);
    if ((tid & 63) == 0) bias[rb] = w2p[0] * d;
  }
}

// ------- split-bf16 MFMA GEMM (r9 structure); packed-in-place epilogue ----
// E = (w1*U).Id^T + bias via hi*hi + hi*lo + lo*hi, mfma_f32_32x32x16_bf16.
// 256 blocks (1/CU), 512 thr = 8 waves (4m x 2n), BK=32, dbuf 96KB LDS.
// Epilogue: x = exp(E+bias-40); packed bf16 pairs (col, col+32) per u32
// written into the FIRST HALF of each out_user row (8KB/row vs 16KB) —
// finalize (same row, same block) unpacks in place. Halves X HBM traffic
// with zero extra workspace.
__global__ __launch_bounds__(512, 2) void user_gemm_mfma(
    const short* __restrict__ planes, const float* __restrict__ bias,
    float* __restrict__ part, float* __restrict__ outU) {
  __shared__ __attribute__((aligned(1024))) char lds[2 * LDSBUF];
  const int tid = threadIdx.x;
  const int lane = tid & 63;
  const int wid = tid >> 6;
  // bijective XCD swizzle: 256 blocks = 8 XCDs x 32 (n-strip chunks per XCD)
  const int ob = (blockIdx.x & 7) * 32 + (blockIdx.x >> 3);
  const int nb = ob >> 3;  // 0..31
  const int mb = ob & 7;   // 0..7
  const int bm = mb * 256, bn = nb * 128;
  const char* gA = (const char*)planes + (size_t)mb * 16 * 32768;
  const char* gB = (const char*)planes + A_BYTES + (size_t)nb * 16 * 16384;
  const int wm = (wid >> 1) * 64;
  const int wn = (wid & 1) * 64;
  const int r32 = lane & 31;
  const int khl = lane >> 5;

  f32x16 acc[2][2] = {};

#define STAGE(ks_, buf_)                                                      \
  {                                                                           \
    const int _ks = (ks_);                                                    \
    char* _dst = lds + (buf_)*LDSBUF;                                         \
    _Pragma("unroll") for (int q = 0; q < 6; ++q) {                           \
      const int off = (q * 512 + tid) * 16;                                   \
      if (q < 4) {                                                            \
        __builtin_amdgcn_global_load_lds(                                     \
            (const __attribute__((address_space(1))) unsigned*)(gA +          \
                (size_t)_ks * 32768 + off),                                   \
            (__attribute__((address_space(3))) unsigned*)(_dst + off), 16, 0, \
            0);                                                               \
      } else {                                                                \
        __builtin_amdgcn_global_load_lds(                                     \
            (const __attribute__((address_space(1))) unsigned*)(gB +          \
                (size_t)_ks * 16384 + (off - 32768)),                         \
            (__attribute__((address_space(3))) unsigned*)(_dst + off), 16, 0, \
            0);                                                               \
      }                                                                       \
    }                                                                         \
  }

  STAGE(0, 0);
  __syncthreads();
  int buf = 0;
  for (int ks = 0; ks < 16; ++ks) {
    if (ks < 15) STAGE(ks + 1, buf ^ 1);
    const char* La = lds + buf * LDSBUF;
    const char* Lb = La + 32768;
#pragma unroll
    for (int s16 = 0; s16 < 2; ++s16) {
      short8 ah[2], al[2], bh[2], bl[2];
#pragma unroll
      for (int i = 0; i < 2; ++i) {
        const int ra = wm + i * 32 + r32;
        const int ga = ((s16 * 2 + khl) ^ (ra & 3) ^ ((ra >> 2) & 3)) * 16;
        ah[i] = *reinterpret_cast<const short8*>(La + ra * 64 + ga);
        al[i] = *reinterpret_cast<const short8*>(La + 16384 + ra * 64 + ga);
        const int rbb = wn + i * 32 + r32;
        const int gb = ((s16 * 2 + khl) ^ (rbb & 3) ^ ((rbb >> 2) & 3)) * 16;
        bh[i] = *reinterpret_cast<const short8*>(Lb + rbb * 64 + gb);
        bl[i] = *reinterpret_cast<const short8*>(Lb + 8192 + rbb * 64 + gb);
      }
#pragma unroll
      for (int i = 0; i < 2; ++i)
#pragma unroll
        for (int j = 0; j < 2; ++j) {
          acc[i][j] = __builtin_amdgcn_mfma_f32_32x32x16_bf16(
              ah[i], bh[j], acc[i][j], 0, 0, 0);
          acc[i][j] = __builtin_amdgcn_mfma_f32_32x32x16_bf16(
              ah[i], bl[j], acc[i][j], 0, 0, 0);
          acc[i][j] = __builtin_amdgcn_mfma_f32_32x32x16_bf16(
              al[i], bh[j], acc[i][j], 0, 0, 0);
        }
    }
    __syncthreads();
    buf ^= 1;
  }
#undef STAGE

  // epilogue: pack x = exp(E + bias - 40) as bf16 pairs into the first half
  // of each out_user row. slot = (bn+wn)/2 + r32; per-(row,nb,n-wave) partial
  // row sums. C/D: col=lane&31, row=(reg&3)+8*(reg>>2)+4*(lane>>5).
  const int slot = ((bn + wn) >> 1) + r32;
  const int pslot = nb * 2 + (wn >> 6);
  float bj[2];
#pragma unroll
  for (int j = 0; j < 2; ++j) bj[j] = bias[bn + wn + j * 32 + r32];
#pragma unroll
  for (int i = 0; i < 2; ++i) {
#pragma unroll
    for (int reg = 0; reg < 16; ++reg) {
      const int rowm = bm + wm + i * 32 + 4 * khl + (reg & 3) + 8 * (reg >> 2);
      const float e0 = __expf(acc[i][0][reg] + bj[0] - EXP_SHIFT);
      const float e1 = __expf(acc[i][1][reg] + bj[1] - EXP_SHIFT);
      const unsigned u = ((unsigned)(unsigned short)f2bf(e0)) |
                         (((unsigned)(unsigned short)f2bf(e1)) << 16);
      reinterpret_cast<unsigned*>(outU + (size_t)rowm * L_DIM)[slot] = u;
      const float hs = half_sum(e0 + e1);
      if (r32 == 0) part[(size_t)rowm * 64 + pslot] = hs;
    }
  }
}

// ------- final kernel: user-unpack+normalize + attn_loc + attn_time ------
// Block s: read own row's packed X (8KB) into regs, barrier, then unpack
// x*sinv into the full 16KB row (same-block RAW, no cross-block hazard).
__global__ __launch_bounds__(256) void finalize_kernel(
    const int* __restrict__ cur, const int* __restrict__ his,
    const float* __restrict__ poi, const int* __restrict__ cur_t,
    const int* __restrict__ his_t, const float* __restrict__ P,
    const float* __restrict__ part, float* __restrict__ out_loc,
    float* __restrict__ out_time, float* __restrict__ out_user) {
  __shared__ __attribute__((aligned(16))) float rowbuf[NPOI];
  __shared__ float Prow[NTIME];
  __shared__ float redm[4];
  __shared__ float reds[4];
  __shared__ float sinv_sh;
  const int s = blockIdx.x;
  const int tid = threadIdx.x;
  if (tid < NTIME) Prow[tid] = P[cur_t[s] * NTIME + tid];
  if (tid < 64) {  // user-row inverse sum from 64 partials
    float p = part[(size_t)s * 64 + tid];
    p = wave_sum(p);
    if (tid == 0) sinv_sh = 1.0f / p;
  }
  // read this row's packed X before any writes to the row
  float* ou = out_user + (size_t)s * L_DIM;
  unsigned xv[8];
  {
    const unsigned* xr = reinterpret_cast<const unsigned*>(ou);
#pragma unroll
    for (int qq = 0; qq < 8; ++qq) xv[qq] = xr[qq * 256 + tid];
  }
  const float* row = poi + (size_t)cur[s] * NPOI;  // 40000B-aligned
  for (int i = tid; i < NPOI / 4; i += 256)
    *reinterpret_cast<float4*>(&rowbuf[i * 4]) =
        *reinterpret_cast<const float4*>(row + i * 4);
  __syncthreads();  // X reads + sinv + rowbuf all complete
  const float sinv = sinv_sh;
#pragma unroll
  for (int qq = 0; qq < 8; ++qq) {
    const int q = qq * 256 + tid;
    const int g = (q >> 5) << 6, r = q & 31;
    union { unsigned uu; float f; } a, b;
    a.uu = xv[qq] << 16;
    b.uu = xv[qq] & 0xffff0000u;
    ou[g + r] = a.f * sinv;
    ou[g + r + 32] = b.f * sinv;
  }
  float v[16];
  float lmax = -1e30f;
#pragma unroll
  for (int j = 0; j < 16; ++j) {
    const int l = j * 256 + tid;
    const float d = rowbuf[his[l]];
    const float e = (d != 0.0f) ? (1.0f / d) : 1e-6f;
    v[j] = e;
    lmax = fmaxf(lmax, e);
  }
  lmax = wave_max(lmax);
  if ((tid & 63) == 0) redm[tid >> 6] = lmax;
  __syncthreads();
  const float m = fmaxf(fmaxf(redm[0], redm[1]), fmaxf(redm[2], redm[3]));
  float lsum = 0.f;
#pragma unroll
  for (int j = 0; j < 16; ++j) {
    v[j] = __expf(v[j] - m);
    lsum += v[j];
  }
  lsum = wave_sum(lsum);
  if ((tid & 63) == 0) reds[tid >> 6] = lsum;
  __syncthreads();
  const float inv = 1.0f / (reds[0] + reds[1] + reds[2] + reds[3]);
  float* ol = out_loc + (size_t)s * L_DIM;
  float* ot = out_time + (size_t)s * L_DIM;
#pragma unroll
  for (int j = 0; j < 16; ++j) {
    const int l = j * 256 + tid;
    ol[l] = v[j] * inv;
    ot[l] = Prow[his_t[l]];
  }
}

extern "C" void kernel_launch(void* const* d_in, const int* in_sizes, int n_in,
                              void* d_out, int out_size, void* d_ws,
                              size_t ws_size, hipStream_t stream) {
  const int* his = (const int*)d_in[0];
  const int* cur = (const int*)d_in[1];
  const int* his_t = (const int*)d_in[2];
  const int* cur_t = (const int*)d_in[3];
  const float* poi = (const float*)d_in[4];
  const float* tsim = (const float*)d_in[5];
  const float* uemb = (const float*)d_in[6];
  const float* idemb = (const float*)d_in[7];
  const float* soc = (const float*)d_in[8];
  const float* w1 = (const float*)d_in[9];
  const float* w2 = (const float*)d_in[10];

  float* out = (float*)d_out;
  float* out_loc = out;
  float* out_time = out + (size_t)S_DIM * L_DIM;
  float* out_user = out + 2 * (size_t)S_DIM * L_DIM;

  // ws layout: planes 12.58MB | bias 16KB | P 9.2KB | part 512KB (~13.1MB,
  // fits: r12 proved ws >= 13.7MB)
  const size_t aux_bytes = (size_t)(L_DIM + NTIME * NTIME + S_DIM * 64) * 4;
  short* planes;
  float* bias;
  if (ws_size >= PLANE_BYTES + aux_bytes) {
    planes = (short*)d_ws;
    bias = (float*)((char*)d_ws + PLANE_BYTES);
  } else {
    // fallback: planes in out_loc plane (written only by finalize, after use)
    planes = (short*)out_loc;
    bias = (float*)d_ws;
  }
  float* P = bias + L_DIM;
  float* part = P + NTIME * NTIME;

  hipLaunchKernelGGL(split_table_kernel,
                     dim3((S_DIM + L_DIM) * 64 / 256 + 1), dim3(256), 0,
                     stream, uemb, idemb, w1, soc, w2, his_t, tsim, planes,
                     bias, P);
  hipLaunchKernelGGL(user_gemm_mfma, dim3(256), dim3(512), 0, stream, planes,
                     bias, part, out_user);
  hipLaunchKernelGGL(finalize_kernel, dim3(S_DIM), dim3(256), 0, stream, cur,
                     his, poi, cur_t, his_t, P, part, out_loc, out_time,
                     out_user);
}

// Round 14
// 83.441 us; speedup vs baseline: 1.1983x; 1.0493x over previous
//
#include <hip/hip_runtime.h>
#include <math.h>

#define S_DIM 2048
#define L_DIM 4096
#define D_DIM 500
#define NPOI 10000
#define NTIME 48
#define EXP_SHIFT 40.0f

typedef __attribute__((ext_vector_type(8))) short short8;
typedef __attribute__((ext_vector_type(16))) float f32x16;

#define A_BYTES 4194304       // 8 mb x 16 ks x 32768
#define PLANE_BYTES 12582912  // A (4 MB) + B (32 nb x 16 ks x 16384)
#define LDSBUF 49152          // [Ahi 16K | Alo 16K | Bhi 8K | Blo 8K]

// ---------------- helpers ----------------
__device__ __forceinline__ float wave_max(float v) {
#pragma unroll
  for (int o = 32; o > 0; o >>= 1) v = fmaxf(v, __shfl_down(v, o, 64));
  return v;
}
__device__ __forceinline__ float wave_sum(float v) {
#pragma unroll
  for (int o = 32; o > 0; o >>= 1) v += __shfl_down(v, o, 64);
  return v;
}
__device__ __forceinline__ float half_sum(float v) {  // sum within 32-lane half
#pragma unroll
  for (int o = 16; o > 0; o >>= 1) v += __shfl_xor(v, o, 64);
  return v;
}
__device__ __forceinline__ short f2bf(float x) {  // RNE f32 -> bf16 bits
  union { float f; unsigned u; } v;
  v.f = x;
  const unsigned r = v.u + 0x7fffu + ((v.u >> 16) & 1u);
  return (short)(r >> 16);
}
__device__ __forceinline__ float bf2f(short h) {
  union { unsigned u; float f; } v;
  v.u = ((unsigned)(unsigned short)h) << 16;
  return v.f;
}

// ------- split (f32 -> GEMM-tiled swizzled hi/lo bf16 planes) + table -----
__global__ __launch_bounds__(256) void split_table_kernel(
    const float* __restrict__ U, const float* __restrict__ Id,
    const float* __restrict__ w1p, const float* __restrict__ soc,
    const float* __restrict__ w2p, const int* __restrict__ his_t,
    const float* __restrict__ T, short* __restrict__ planes,
    float* __restrict__ bias, float* __restrict__ P) {
  const int tid = threadIdx.x;
  if (blockIdx.x == gridDim.x - 1) {  // ---- time table block ----
    __shared__ int cnt[NTIME];
    __shared__ float Ts[NTIME * NTIME];
    if (tid < NTIME) cnt[tid] = 0;
    __syncthreads();
    for (int l = tid; l < L_DIM; l += 256) atomicAdd(&cnt[his_t[l]], 1);
    for (int i = tid; i < NTIME * NTIME; i += 256) Ts[i] = T[i];
    __syncthreads();
    if (tid < NTIME) {
      float m = -1e30f;
      for (int t = 0; t < NTIME; ++t) m = fmaxf(m, Ts[tid * NTIME + t]);
      float den = 0.f;
      for (int t = 0; t < NTIME; ++t)
        den += (float)cnt[t] * __expf(Ts[tid * NTIME + t] - m);
      const float inv = 1.0f / den;
      for (int t = 0; t < NTIME; ++t)
        P[tid * NTIME + t] = __expf(Ts[tid * NTIME + t] - m) * inv;
    }
    return;
  }
  const int chunk = blockIdx.x * 256 + tid;
  const int row = chunk >> 6;  // 0..6143
  const int lq = chunk & 63;   // 8-elem granule index along K
  const bool isA = row < S_DIM;
  const float scale = isA ? w1p[0] : 1.0f;
  const float* src = isA ? (U + (size_t)row * D_DIM)
                         : (Id + (size_t)(row - S_DIM) * D_DIM);
  const int k0 = lq * 8;
  float dot = 0.f;
  short h[8], l[8];
#pragma unroll
  for (int e = 0; e < 8; ++e) {
    const int k = k0 + e;
    const float v = (k < D_DIM) ? src[k] : 0.0f;
    if (!isA && k < D_DIM) dot += v * soc[k];
    const float x = scale * v;
    const short hb = f2bf(x);
    h[e] = hb;
    l[e] = f2bf(x - bf2f(hb));
  }
  const int ks = lq >> 2, g = lq & 3;
  if (isA) {
    const int mb = row >> 8, rin = row & 255;
    const int gs = g ^ (rin & 3) ^ ((rin >> 2) & 3);
    char* base =
        (char*)planes + (size_t)(mb * 16 + ks) * 32768 + rin * 64 + gs * 16;
    *reinterpret_cast<int4*>(base) = *reinterpret_cast<const int4*>(h);
    *reinterpret_cast<int4*>(base + 16384) = *reinterpret_cast<const int4*>(l);
  } else {
    const int rb = row - S_DIM;
    const int nb = rb >> 7, rin = rb & 127;
    const int gs = g ^ (rin & 3) ^ ((rin >> 2) & 3);
    char* base = (char*)planes + A_BYTES + (size_t)(nb * 16 + ks) * 16384 +
                 rin * 64 + gs * 16;
    *reinterpret_cast<int4*>(base) = *reinterpret_cast<const int4*>(h);
    *reinterpret_cast<int4*>(base + 8192) = *reinterpret_cast<const int4*>(l);
    const float d = wave_sum(dot);
    if ((tid & 63) == 0) bias[rb] = w2p[0] * d;
  }
}

// ------- split-bf16 MFMA GEMM; counted-vmcnt pipeline (T4) ----------------
// E = (w1*U).Id^T + bias via hi*hi + hi*lo + lo*hi, mfma_f32_32x32x16_bf16.
// 256 blocks (1/CU), 512 thr = 8 waves (4m x 2n), BK=32, dbuf 96KB LDS.
// Loop: vmcnt(6) (own 6 loads of step ks done; 6 of ks+1 in flight) ->
// barrier -> compute -> barrier -> STAGE(ks+2) into freed buf. Loads stay in
// flight across barriers (no full drain). Last iter peels to vmcnt(0).
// Epilogue: packed bf16 exp pairs into first half of each out_user row.
__global__ __launch_bounds__(512, 2) void user_gemm_mfma(
    const short* __restrict__ planes, const float* __restrict__ bias,
    float* __restrict__ part, float* __restrict__ outU) {
  __shared__ __attribute__((aligned(1024))) char lds[2 * LDSBUF];
  const int tid = threadIdx.x;
  const int lane = tid & 63;
  const int wid = tid >> 6;
  // bijective XCD swizzle: 256 blocks = 8 XCDs x 32 (n-strip chunks per XCD)
  const int ob = (blockIdx.x & 7) * 32 + (blockIdx.x >> 3);
  const int nb = ob >> 3;  // 0..31
  const int mb = ob & 7;   // 0..7
  const int bm = mb * 256, bn = nb * 128;
  const char* gA = (const char*)planes + (size_t)mb * 16 * 32768;
  const char* gB = (const char*)planes + A_BYTES + (size_t)nb * 16 * 16384;
  const int wm = (wid >> 1) * 64;
  const int wn = (wid & 1) * 64;
  const int r32 = lane & 31;
  const int khl = lane >> 5;

  f32x16 acc[2][2] = {};

#define STAGE(ks_, buf_)                                                      \
  {                                                                           \
    const int _ks = (ks_);                                                    \
    char* _dst = lds + (buf_)*LDSBUF;                                         \
    _Pragma("unroll") for (int q = 0; q < 6; ++q) {                           \
      const int off = (q * 512 + tid) * 16;                                   \
      if (q < 4) {                                                            \
        __builtin_amdgcn_global_load_lds(                                     \
            (const __attribute__((address_space(1))) unsigned*)(gA +          \
                (size_t)_ks * 32768 + off),                                   \
            (__attribute__((address_space(3))) unsigned*)(_dst + off), 16, 0, \
            0);                                                               \
      } else {                                                                \
        __builtin_amdgcn_global_load_lds(                                     \
            (const __attribute__((address_space(1))) unsigned*)(gB +          \
                (size_t)_ks * 16384 + (off - 32768)),                         \
            (__attribute__((address_space(3))) unsigned*)(_dst + off), 16, 0, \
            0);                                                               \
      }                                                                       \
    }                                                                         \
  }

  STAGE(0, 0);
  STAGE(1, 1);
  int buf = 0;
  for (int ks = 0; ks < 16; ++ks) {
    if (ks < 15) {
      asm volatile("s_waitcnt vmcnt(6)" ::: "memory");
    } else {
      asm volatile("s_waitcnt vmcnt(0)" ::: "memory");
    }
    __builtin_amdgcn_sched_barrier(0);
    __builtin_amdgcn_s_barrier();  // all waves' step-ks loads landed
    const char* La = lds + buf * LDSBUF;
    const char* Lb = La + 32768;
#pragma unroll
    for (int s16 = 0; s16 < 2; ++s16) {
      short8 ah[2], al[2], bh[2], bl[2];
#pragma unroll
      for (int i = 0; i < 2; ++i) {
        const int ra = wm + i * 32 + r32;
        const int ga = ((s16 * 2 + khl) ^ (ra & 3) ^ ((ra >> 2) & 3)) * 16;
        ah[i] = *reinterpret_cast<const short8*>(La + ra * 64 + ga);
        al[i] = *reinterpret_cast<const short8*>(La + 16384 + ra * 64 + ga);
        const int rbb = wn + i * 32 + r32;
        const int gb = ((s16 * 2 + khl) ^ (rbb & 3) ^ ((rbb >> 2) & 3)) * 16;
        bh[i] = *reinterpret_cast<const short8*>(Lb + rbb * 64 + gb);
        bl[i] = *reinterpret_cast<const short8*>(Lb + 8192 + rbb * 64 + gb);
      }
#pragma unroll
      for (int i = 0; i < 2; ++i)
#pragma unroll
        for (int j = 0; j < 2; ++j) {
          acc[i][j] = __builtin_amdgcn_mfma_f32_32x32x16_bf16(
              ah[i], bh[j], acc[i][j], 0, 0, 0);
          acc[i][j] = __builtin_amdgcn_mfma_f32_32x32x16_bf16(
              ah[i], bl[j], acc[i][j], 0, 0, 0);
          acc[i][j] = __builtin_amdgcn_mfma_f32_32x32x16_bf16(
              al[i], bh[j], acc[i][j], 0, 0, 0);
        }
    }
    // all of this wave's ds_reads were consumed by the MFMAs above
    // (compiler-inserted lgkmcnt), so after this barrier buf is free.
    __builtin_amdgcn_s_barrier();
    __builtin_amdgcn_sched_barrier(0);
    if (ks + 2 < 16) STAGE(ks + 2, buf);
    buf ^= 1;
  }
#undef STAGE

  // epilogue: pack x = exp(E + bias - 40) as bf16 pairs into the first half
  // of each out_user row. C/D: col=lane&31, row=(reg&3)+8*(reg>>2)+4*(lane>>5)
  const int slot = ((bn + wn) >> 1) + r32;
  const int pslot = nb * 2 + (wn >> 6);
  float bj[2];
#pragma unroll
  for (int j = 0; j < 2; ++j) bj[j] = bias[bn + wn + j * 32 + r32];
#pragma unroll
  for (int i = 0; i < 2; ++i) {
#pragma unroll
    for (int reg = 0; reg < 16; ++reg) {
      const int rowm = bm + wm + i * 32 + 4 * khl + (reg & 3) + 8 * (reg >> 2);
      const float e0 = __expf(acc[i][0][reg] + bj[0] - EXP_SHIFT);
      const float e1 = __expf(acc[i][1][reg] + bj[1] - EXP_SHIFT);
      const unsigned u = ((unsigned)(unsigned short)f2bf(e0)) |
                         (((unsigned)(unsigned short)f2bf(e1)) << 16);
      reinterpret_cast<unsigned*>(outU + (size_t)rowm * L_DIM)[slot] = u;
      const float hs = half_sum(e0 + e1);
      if (r32 == 0) part[(size_t)rowm * 64 + pslot] = hs;
    }
  }
}

// ------- final kernel: user-unpack+normalize + attn_loc + attn_time ------
__global__ __launch_bounds__(256) void finalize_kernel(
    const int* __restrict__ cur, const int* __restrict__ his,
    const float* __restrict__ poi, const int* __restrict__ cur_t,
    const int* __restrict__ his_t, const float* __restrict__ P,
    const float* __restrict__ part, float* __restrict__ out_loc,
    float* __restrict__ out_time, float* __restrict__ out_user) {
  __shared__ __attribute__((aligned(16))) float rowbuf[NPOI];
  __shared__ float Prow[NTIME];
  __shared__ float redm[4];
  __shared__ float reds[4];
  __shared__ float sinv_sh;
  const int s = blockIdx.x;
  const int tid = threadIdx.x;
  if (tid < NTIME) Prow[tid] = P[cur_t[s] * NTIME + tid];
  if (tid < 64) {  // user-row inverse sum from 64 partials
    float p = part[(size_t)s * 64 + tid];
    p = wave_sum(p);
    if (tid == 0) sinv_sh = 1.0f / p;
  }
  // read this row's packed X before any writes to the row
  float* ou = out_user + (size_t)s * L_DIM;
  unsigned xv[8];
  {
    const unsigned* xr = reinterpret_cast<const unsigned*>(ou);
#pragma unroll
    for (int qq = 0; qq < 8; ++qq) xv[qq] = xr[qq * 256 + tid];
  }
  // stage poi row via global_load_lds (direct HBM->LDS, no VGPR roundtrip)
  {
    const char* row = (const char*)(poi + (size_t)cur[s] * NPOI);
    char* dst = (char*)rowbuf;
    for (int c = tid; c < NPOI / 4; c += 256) {  // 2500 16B chunks
      __builtin_amdgcn_global_load_lds(
          (const __attribute__((address_space(1))) unsigned*)(row + c * 16),
          (__attribute__((address_space(3))) unsigned*)(dst + c * 16), 16, 0,
          0);
    }
  }
  __syncthreads();  // drains vmcnt (gload_lds) + sinv + X reads
  const float sinv = sinv_sh;
#pragma unroll
  for (int qq = 0; qq < 8; ++qq) {
    const int q = qq * 256 + tid;
    const int g = (q >> 5) << 6, r = q & 31;
    union { unsigned uu; float f; } a, b;
    a.uu = xv[qq] << 16;
    b.uu = xv[qq] & 0xffff0000u;
    ou[g + r] = a.f * sinv;
    ou[g + r + 32] = b.f * sinv;
  }
  float v[16];
  float lmax = -1e30f;
#pragma unroll
  for (int j = 0; j < 16; ++j) {
    const int l = j * 256 + tid;
    const float d = rowbuf[his[l]];
    const float e = (d != 0.0f) ? (1.0f / d) : 1e-6f;
    v[j] = e;
    lmax = fmaxf(lmax, e);
  }
  lmax = wave_max(lmax);
  if ((tid & 63) == 0) redm[tid >> 6] = lmax;
  __syncthreads();
  const float m = fmaxf(fmaxf(redm[0], redm[1]), fmaxf(redm[2], redm[3]));
  float lsum = 0.f;
#pragma unroll
  for (int j = 0; j < 16; ++j) {
    v[j] = __expf(v[j] - m);
    lsum += v[j];
  }
  lsum = wave_sum(lsum);
  if ((tid & 63) == 0) reds[tid >> 6] = lsum;
  __syncthreads();
  const float inv = 1.0f / (reds[0] + reds[1] + reds[2] + reds[3]);
  float* ol = out_loc + (size_t)s * L_DIM;
  float* ot = out_time + (size_t)s * L_DIM;
#pragma unroll
  for (int j = 0; j < 16; ++j) {
    const int l = j * 256 + tid;
    ol[l] = v[j] * inv;
    ot[l] = Prow[his_t[l]];
  }
}

extern "C" void kernel_launch(void* const* d_in, const int* in_sizes, int n_in,
                              void* d_out, int out_size, void* d_ws,
                              size_t ws_size, hipStream_t stream) {
  const int* his = (const int*)d_in[0];
  const int* cur = (const int*)d_in[1];
  const int* his_t = (const int*)d_in[2];
  const int* cur_t = (const int*)d_in[3];
  const float* poi = (const float*)d_in[4];
  const float* tsim = (const float*)d_in[5];
  const float* uemb = (const float*)d_in[6];
  const float* idemb = (const float*)d_in[7];
  const float* soc = (const float*)d_in[8];
  const float* w1 = (const float*)d_in[9];
  const float* w2 = (const float*)d_in[10];

  float* out = (float*)d_out;
  float* out_loc = out;
  float* out_time = out + (size_t)S_DIM * L_DIM;
  float* out_user = out + 2 * (size_t)S_DIM * L_DIM;

  // ws layout: planes 12.58MB | bias 16KB | P 9.2KB | part 512KB (~13.1MB)
  const size_t aux_bytes = (size_t)(L_DIM + NTIME * NTIME + S_DIM * 64) * 4;
  short* planes;
  float* bias;
  if (ws_size >= PLANE_BYTES + aux_bytes) {
    planes = (short*)d_ws;
    bias = (float*)((char*)d_ws + PLANE_BYTES);
  } else {
    // fallback: planes in out_loc plane (written only by finalize, after use)
    planes = (short*)out_loc;
    bias = (float*)d_ws;
  }
  float* P = bias + L_DIM;
  float* part = P + NTIME * NTIME;

  hipLaunchKernelGGL(split_table_kernel,
                     dim3((S_DIM + L_DIM) * 64 / 256 + 1), dim3(256), 0,
                     stream, uemb, idemb, w1, soc, w2, his_t, tsim, planes,
                     bias, P);
  hipLaunchKernelGGL(user_gemm_mfma, dim3(256), dim3(512), 0, stream, planes,
                     bias, part, out_user);
  hipLaunchKernelGGL(finalize_kernel, dim3(S_DIM), dim3(256), 0, stream, cur,
                     his, poi, cur_t, his_t, P, part, out_loc, out_time,
                     out_user);
}